// Round 4
// baseline (205.543 us; speedup 1.0000x reference)
//
#include <hip/hip_runtime.h>

// ---------------------------------------------------------------------------
// GeometricRound fused: geo(Cl(3)) -> mix -> LayerNorm -> MLP(g/u 128->512,
// silu*mul, down 512->128) -> +x.  B=4 T=4096 N=8 D=128 F=512, M=131072 rows.
//
// k_prep : sigmoid-combine interaction weights -> 36 coeffs; bf16 + transpose
//          + XOR-swizzle w_gate/w_up/w_down into d_ws (8 chunks x 16 KiB each).
// k_fused: 512 blocks x 256 thr, wave owns 64 rows.
//   phase1: geo+mix -> f32 LDS transpose (per-wave 8KB scratch) -> LN stats
//           (31 adds + 2 shfl_xor) -> normed bf16 MFMA B-frags in regs (bn).
//           chunk-0 weights stage concurrently via global_load_lds.
//   loop(8 F-chunks of 64): GEMM1 (Wg/Wu from LDS x bn) -> silu -> h_t (LDS,
//           swizzled) -> GEMM2 (Wd x h) -> f32 acc; 2 barriers/chunk.
//   epilogue: out = x + acc.
// LDS = 48K wbuf + 4x8K scratch/h_t = 80 KiB -> target 2 blocks/CU.
// ---------------------------------------------------------------------------

typedef __bf16 bf16x8 __attribute__((ext_vector_type(8)));
typedef float  f32x4  __attribute__((ext_vector_type(4)));

#define MFMA16(a, b, c) __builtin_amdgcn_mfma_f32_16x16x32_bf16((a), (b), (c), 0, 0, 0)

constexpr int OFF_WG = 0;        // 8 chunks x 16 KiB  (w_gate, [f'][k] swizzled)
constexpr int OFF_WU = 131072;   // 8 chunks x 16 KiB  (w_up)
constexpr int OFF_WD = 262144;   // 8 chunks x 16 KiB  (w_down, [d][f'] swizzled)
constexpr int OFF_C  = 393216;   // 38 f32: 36 geo coeffs, gate, 1-gate

__device__ __forceinline__ float fexp2(float x) {
  float r; asm("v_exp_f32 %0, %1" : "=v"(r) : "v"(x)); return r;
}
__device__ __forceinline__ float frcp(float x) {
  float r; asm("v_rcp_f32 %0, %1" : "=v"(r) : "v"(x)); return r;
}
__device__ __forceinline__ float fsigmoid(float x) {
  return frcp(1.f + fexp2(-1.44269504088896f * x));
}
__device__ __forceinline__ unsigned cvtbf(float f) {   // f32->bf16 RNE
  unsigned u = __builtin_bit_cast(unsigned, f);
  return (u + 0x7fffu + ((u >> 16) & 1u)) >> 16;
}
__device__ __forceinline__ unsigned pack2(float a, float b) {
  return cvtbf(a) | (cvtbf(b) << 16);
}

// unordered pair table for geo basis k=1..7 (from _reduce_product; e_i^2=+1)
__device__ constexpr int PIdx[7][4][2] = {
  {{0,1},{2,4},{3,5},{6,7}},   // k=1 (e1)
  {{0,2},{1,4},{3,6},{5,7}},   // k=2 (e2)
  {{0,3},{1,5},{2,6},{4,7}},   // k=3 (e3)
  {{0,4},{1,2},{3,7},{5,6}},   // k=4 (e12)
  {{0,5},{1,3},{2,7},{4,6}},   // k=5 (e13)
  {{0,6},{1,7},{2,3},{4,5}},   // k=6 (e23)
  {{0,7},{1,6},{2,5},{3,4}}};  // k=7 (e123)

// ---- kernel 0: prep (unchanged, verified by r3 pass) -----------------------
__global__ __launch_bounds__(256) void k_prep(
    const float* __restrict__ W, const float* __restrict__ wg,
    const float* __restrict__ wu, const float* __restrict__ wd,
    const float* __restrict__ gg, char* __restrict__ ws) {
  int gid = blockIdx.x * 256 + threadIdx.x;
  if (gid < 65536) {
    int f = gid & 511, k = gid >> 9;
    unsigned short v = (unsigned short)cvtbf(wg[k * 512 + f]);
    int fl = f & 63;
    int off = OFF_WG + (f >> 6) * 16384 + ((fl * 256 + k * 2) ^ ((f & 7) << 4));
    *(unsigned short*)(ws + off) = v;
  } else if (gid < 131072) {
    int t = gid - 65536;
    int f = t & 511, k = t >> 9;
    unsigned short v = (unsigned short)cvtbf(wu[k * 512 + f]);
    int fl = f & 63;
    int off = OFF_WU + (f >> 6) * 16384 + ((fl * 256 + k * 2) ^ ((f & 7) << 4));
    *(unsigned short*)(ws + off) = v;
  } else {
    int t = gid - 131072;
    int d = t & 127, f = t >> 7;
    unsigned short v = (unsigned short)cvtbf(wd[f * 128 + d]);
    int fl = f & 63;
    int off = OFF_WD + (f >> 6) * 16384 + ((d * 128 + fl * 2) ^ ((d & 7) << 4));
    *(unsigned short*)(ws + off) = v;
  }
  if (blockIdx.x == 0 && threadIdx.x == 0) {
    float s[64];
    for (int i = 0; i < 64; ++i) s[i] = fsigmoid(W[i]);
    float* C = (float*)(ws + OFF_C);
#define Sij(i, j) s[(i) * 8 + (j)]
    for (int i = 0; i < 8; ++i) C[i] = (i < 4 ? 1.f : -1.f) * Sij(i, i);
    C[8]  =  Sij(0,1) + Sij(1,0);  C[9]  = -Sij(2,4) + Sij(4,2);
    C[10] = -Sij(3,5) + Sij(5,3);  C[11] = -Sij(6,7) - Sij(7,6);
    C[12] =  Sij(0,2) + Sij(2,0);  C[13] =  Sij(1,4) - Sij(4,1);
    C[14] = -Sij(3,6) + Sij(6,3);  C[15] =  Sij(5,7) + Sij(7,5);
    C[16] =  Sij(0,3) + Sij(3,0);  C[17] =  Sij(1,5) - Sij(5,1);
    C[18] =  Sij(2,6) - Sij(6,2);  C[19] = -Sij(4,7) - Sij(7,4);
    C[20] =  Sij(0,4) + Sij(4,0);  C[21] =  Sij(1,2) - Sij(2,1);
    C[22] =  Sij(3,7) + Sij(7,3);  C[23] = -Sij(5,6) + Sij(6,5);
    C[24] =  Sij(0,5) + Sij(5,0);  C[25] =  Sij(1,3) - Sij(3,1);
    C[26] = -Sij(2,7) - Sij(7,2);  C[27] =  Sij(4,6) - Sij(6,4);
    C[28] =  Sij(0,6) + Sij(6,0);  C[29] =  Sij(1,7) + Sij(7,1);
    C[30] =  Sij(2,3) - Sij(3,2);  C[31] = -Sij(4,5) + Sij(5,4);
    C[32] =  Sij(0,7) + Sij(7,0);  C[33] =  Sij(1,6) + Sij(6,1);
    C[34] = -Sij(2,5) - Sij(5,2);  C[35] =  Sij(3,4) + Sij(4,3);
#undef Sij
    float gate = fsigmoid(gg[0]);
    C[36] = gate; C[37] = 1.f - gate;
  }
}

// ---- fused kernel ---------------------------------------------------------
__global__ __launch_bounds__(256, 2) void k_fused(
    const float* __restrict__ x,
    const float* __restrict__ gamma,
    const float* __restrict__ beta,
    const float* __restrict__ cws,
    float* __restrict__ out,
    const char* __restrict__ ws) {
  __shared__ __align__(16) char lds[81920];  // [0,48K) wbuf; [48K,80K) scratch/h_t
  const int tid = threadIdx.x, l = tid & 63, w = tid >> 6;
  const int r16 = l & 15, g4 = l >> 4;
  const long wrow0 = (long)blockIdx.x * 256 + (long)w * 64;

  char* scr = lds + 49152 + w * 8192;  // per-wave 8 KiB scratch, later h_t

#define STAGE(fcv)                                                             \
  _Pragma("unroll") for (int j = 0; j < 12; ++j) {                             \
    int o = (w * 12 + j) * 1024 + l * 16;                                      \
    const char* src = ws + (o >> 14) * 131072 + (fcv) * 16384 + (o & 16383);   \
    __builtin_amdgcn_global_load_lds(                                          \
        (const __attribute__((address_space(1))) unsigned*)src,                \
        (__attribute__((address_space(3))) unsigned*)(lds + (w * 12 + j) * 1024), \
        16, 0, 0);                                                             \
  }

  STAGE(0);  // chunk-0 weights land under phase 1

  // ---- phase 1: geo + mix + LN -> bn fragments ----------------------------
  float C[38];
#pragma unroll
  for (int i = 0; i < 38; ++i) C[i] = cws[i];  // uniform -> scalar
  const float gate = C[36], omg = C[37];

  bf16x8 bn[4][4];  // [row-tile][ks]: lane(g4,r16) holds k=ks*32+g4*8+e, row r16
#pragma unroll
  for (int p = 0; p < 4; ++p) {
    // two bt-groups of 8 rows -> mixed f32 into scratch [16][128] (swizzled)
#pragma unroll
    for (int hB = 0; hB < 2; ++hB) {
      const long r0 = wrow0 + p * 16 + hB * 8;
      float xa[8], xb[8];
#pragma unroll
      for (int n = 0; n < 8; ++n) {
        float2 v = *(const float2*)(x + (size_t)(r0 + n) * 128 + 2 * l);
        xa[n] = v.x; xb[n] = v.y;
      }
      float ga[8], gb[8];
      {
        float a0 = C[0] * xa[0] * xa[0], b0 = C[0] * xb[0] * xb[0];
#pragma unroll
        for (int i = 1; i < 8; ++i) {
          a0 = fmaf(C[i], xa[i] * xa[i], a0);
          b0 = fmaf(C[i], xb[i] * xb[i], b0);
        }
        ga[0] = a0; gb[0] = b0;
#pragma unroll
        for (int k = 1; k < 8; ++k) {
          float ta = 0.f, tb = 0.f;
#pragma unroll
          for (int q = 0; q < 4; ++q) {
            const int i = PIdx[k - 1][q][0], jj = PIdx[k - 1][q][1];
            const float c = C[8 + (k - 1) * 4 + q];
            ta = fmaf(c, xa[i] * xa[jj], ta);
            tb = fmaf(c, xb[i] * xb[jj], tb);
          }
          ga[k] = ta; gb[k] = tb;
        }
      }
#pragma unroll
      for (int n = 0; n < 8; ++n) {
        float2 m2;
        m2.x = fmaf(gate, ga[n], omg * xa[n]);
        m2.y = fmaf(gate, gb[n], omg * xb[n]);
        const int sr = hB * 8 + n;  // sr&7 == n
        *(float2*)(scr + sr * 512 + ((l * 8) ^ (n << 4))) = m2;
      }
    }
    // fragment read (transpose): lane(g4,r16) <- row r16, k = ks*32+g4*8+e
    f32x4 mx[4][2];
    float s = 0.f, ss = 0.f;
    const int swr = (r16 & 7) << 4;
#pragma unroll
    for (int ks = 0; ks < 4; ++ks)
#pragma unroll
      for (int hh = 0; hh < 2; ++hh) {
        f32x4 v = *(const f32x4*)(scr + r16 * 512 +
                                  ((ks * 128 + g4 * 32 + hh * 16) ^ swr));
        mx[ks][hh] = v;
#pragma unroll
        for (int e = 0; e < 4; ++e) { s += v[e]; ss = fmaf(v[e], v[e], ss); }
      }
    s  += __shfl_xor(s, 16);  s  += __shfl_xor(s, 32);
    ss += __shfl_xor(ss, 16); ss += __shfl_xor(ss, 32);
    const float mean = s * (1.f / 128.f);
    const float var  = fmaf(-mean, mean, ss * (1.f / 128.f));
    const float rstd = rsqrtf(var + 1e-5f);
#pragma unroll
    for (int ks = 0; ks < 4; ++ks) {
      const float4 gm0 = *(const float4*)(gamma + ks * 32 + g4 * 8);
      const float4 gm1 = *(const float4*)(gamma + ks * 32 + g4 * 8 + 4);
      const float4 be0 = *(const float4*)(beta + ks * 32 + g4 * 8);
      const float4 be1 = *(const float4*)(beta + ks * 32 + g4 * 8 + 4);
      float nv[8];
      nv[0] = fmaf((mx[ks][0][0] - mean) * rstd, gm0.x, be0.x);
      nv[1] = fmaf((mx[ks][0][1] - mean) * rstd, gm0.y, be0.y);
      nv[2] = fmaf((mx[ks][0][2] - mean) * rstd, gm0.z, be0.z);
      nv[3] = fmaf((mx[ks][0][3] - mean) * rstd, gm0.w, be0.w);
      nv[4] = fmaf((mx[ks][1][0] - mean) * rstd, gm1.x, be1.x);
      nv[5] = fmaf((mx[ks][1][1] - mean) * rstd, gm1.y, be1.y);
      nv[6] = fmaf((mx[ks][1][2] - mean) * rstd, gm1.z, be1.z);
      nv[7] = fmaf((mx[ks][1][3] - mean) * rstd, gm1.w, be1.w);
      uint4 uv;
      uv.x = pack2(nv[0], nv[1]); uv.y = pack2(nv[2], nv[3]);
      uv.z = pack2(nv[4], nv[5]); uv.w = pack2(nv[6], nv[7]);
      bn[p][ks] = __builtin_bit_cast(bf16x8, uv);
    }
  }

  __syncthreads();  // chunk-0 weights staged & visible; scratch now free

  // ---- chunk loop ---------------------------------------------------------
  f32x4 acc[8][4];
#pragma unroll
  for (int dt = 0; dt < 8; ++dt)
#pragma unroll
    for (int rt = 0; rt < 4; ++rt) acc[dt][rt] = f32x4{0.f, 0.f, 0.f, 0.f};

  const char* lwg = lds;
  const char* lwu = lds + 16384;
  const char* lwd = lds + 32768;
  char* lht = scr;  // per-wave [64 rows][64 f] bf16, swizzled

  for (int fc = 0; fc < 8; ++fc) {
    // GEMM1: C'[f][row] = Wg[f][k] x normed[row][k]; silu*up -> h_t
#pragma unroll
    for (int ft = 0; ft < 4; ++ft) {
      const int fl = ft * 16 + r16, swzf = (fl & 7) << 4;
      bf16x8 ag[4], au[4];
#pragma unroll
      for (int ks = 0; ks < 4; ++ks) {
        const int kb = ks * 64 + g4 * 16;
        ag[ks] = *(const bf16x8*)(lwg + fl * 256 + (kb ^ swzf));
        au[ks] = *(const bf16x8*)(lwu + fl * 256 + (kb ^ swzf));
      }
#pragma unroll
      for (int rt = 0; rt < 4; ++rt) {
        f32x4 cg = {0.f, 0.f, 0.f, 0.f}, cu = {0.f, 0.f, 0.f, 0.f};
#pragma unroll
        for (int ks = 0; ks < 4; ++ks) {
          cg = MFMA16(ag[ks], bn[rt][ks], cg);
          cu = MFMA16(au[ks], bn[rt][ks], cu);
        }
        const float h0 = cg[0] * cu[0] * frcp(1.f + fexp2(-1.44269504f * cg[0]));
        const float h1 = cg[1] * cu[1] * frcp(1.f + fexp2(-1.44269504f * cg[1]));
        const float h2 = cg[2] * cu[2] * frcp(1.f + fexp2(-1.44269504f * cg[2]));
        const float h3 = cg[3] * cu[3] * frcp(1.f + fexp2(-1.44269504f * cg[3]));
        uint2 hv; hv.x = pack2(h0, h1); hv.y = pack2(h2, h3);
        const int row = rt * 16 + r16;
        *(uint2*)(lht + row * 128 + ((ft * 32 + g4 * 8) ^ ((row & 7) << 4))) = hv;
      }
    }
    // GEMM2: out'[d][row] += Wd[d][f'] x h[row][f']
    bf16x8 hb[4][2];
#pragma unroll
    for (int rt = 0; rt < 4; ++rt)
#pragma unroll
      for (int k2 = 0; k2 < 2; ++k2) {
        const int row = rt * 16 + r16;
        hb[rt][k2] = *(const bf16x8*)(lht + row * 128 +
                                      ((k2 * 64 + g4 * 16) ^ ((row & 7) << 4)));
      }
#pragma unroll
    for (int dt = 0; dt < 8; ++dt) {
      const int d = dt * 16 + r16, swzd = (d & 7) << 4;
      bf16x8 w0 = *(const bf16x8*)(lwd + d * 128 + ((g4 * 16) ^ swzd));
      bf16x8 w1 = *(const bf16x8*)(lwd + d * 128 + ((64 + g4 * 16) ^ swzd));
#pragma unroll
      for (int rt = 0; rt < 4; ++rt) {
        acc[dt][rt] = MFMA16(w0, hb[rt][0], acc[dt][rt]);
        acc[dt][rt] = MFMA16(w1, hb[rt][1], acc[dt][rt]);
      }
    }
    if (fc < 7) {
      __syncthreads();   // all waves done reading wbuf
      STAGE(fc + 1);
      __syncthreads();   // next chunk visible
    }
  }
#undef STAGE

  // ---- epilogue: out = x + acc -------------------------------------------
#pragma unroll
  for (int dt = 0; dt < 8; ++dt)
#pragma unroll
    for (int rt = 0; rt < 4; ++rt) {
      const size_t row = (size_t)(wrow0 + rt * 16 + r16);
      const int db = dt * 16 + g4 * 4;
      const float4 xv = *(const float4*)(x + row * 128 + db);
      float4 o;
      o.x = acc[dt][rt][0] + xv.x;
      o.y = acc[dt][rt][1] + xv.y;
      o.z = acc[dt][rt][2] + xv.z;
      o.w = acc[dt][rt][3] + xv.w;
      *(float4*)(out + row * 128 + db) = o;
    }
}

// ---------------------------------------------------------------------------

extern "C" void kernel_launch(void* const* d_in, const int* in_sizes, int n_in,
                              void* d_out, int out_size, void* d_ws, size_t ws_size,
                              hipStream_t stream) {
  (void)in_sizes; (void)n_in; (void)out_size; (void)ws_size;
  const float* x     = (const float*)d_in[0];
  const float* W     = (const float*)d_in[1];
  const float* wg    = (const float*)d_in[2];
  const float* wu    = (const float*)d_in[3];
  const float* wd    = (const float*)d_in[4];
  const float* gamma = (const float*)d_in[5];
  const float* beta  = (const float*)d_in[6];
  const float* gg    = (const float*)d_in[7];
  char* ws = (char*)d_ws;

  k_prep<<<768, 256, 0, stream>>>(W, wg, wu, wd, gg, ws);
  k_fused<<<512, 256, 0, stream>>>(x, gamma, beta, (const float*)(ws + OFF_C),
                                   (float*)d_out, ws);
}

// Round 5
// 201.982 us; speedup vs baseline: 1.0176x; 1.0176x over previous
//
#include <hip/hip_runtime.h>

// ---------------------------------------------------------------------------
// GeometricRound fused: geo(Cl(3)) -> mix -> LayerNorm -> MLP(g/u 128->512,
// silu*mul, down 512->128) -> +x.  B=4 T=4096 N=8 D=128 F=512, M=131072 rows.
//
// k_prep : sigmoid-combine interaction weights -> 36 coeffs; bf16-convert
//          w_gate/w_up/w_down into PER-LANE MFMA FRAGMENT layout in d_ws:
//            wg/wu: [fc][ks][g4][fl][e]  (16 KiB per chunk)
//            wd   : [fc][k2][g4][d ][e]  (16 KiB per chunk)
//          so k_fused loads fragments straight from global (L2-resident).
// k_fused: 512 blocks x 256 thr, wave owns 64 rows. NO __syncthreads at all.
//   phase1: geo+mix -> f32 LDS transpose (per-wave 8KB scratch) -> LN ->
//           normed bf16 MFMA B-frags in regs (bn).
//   loop(8 F-chunks of 64): GEMM1 (Wg/Wu frags from GLOBAL x bn) -> silu ->
//           h_t (per-wave LDS, swizzled) -> GEMM2 (Wd frags from GLOBAL x h)
//           -> f32 acc.  Waves fully independent; latency hidden by ILP+TLP.
//   epilogue: out = x + acc.
// LDS = 4 x 8 KiB scratch/h_t = 32 KiB/block.
// ---------------------------------------------------------------------------

typedef __bf16 bf16x8 __attribute__((ext_vector_type(8)));
typedef float  f32x4  __attribute__((ext_vector_type(4)));

#define MFMA16(a, b, c) __builtin_amdgcn_mfma_f32_16x16x32_bf16((a), (b), (c), 0, 0, 0)

constexpr int OFF_WG = 0;        // 8 chunks x 16 KiB
constexpr int OFF_WU = 131072;   // 8 chunks x 16 KiB
constexpr int OFF_WD = 262144;   // 8 chunks x 16 KiB
constexpr int OFF_C  = 393216;   // 38 f32: 36 geo coeffs, gate, 1-gate

__device__ __forceinline__ float fexp2(float x) {
  float r; asm("v_exp_f32 %0, %1" : "=v"(r) : "v"(x)); return r;
}
__device__ __forceinline__ float frcp(float x) {
  float r; asm("v_rcp_f32 %0, %1" : "=v"(r) : "v"(x)); return r;
}
__device__ __forceinline__ float fsigmoid(float x) {
  return frcp(1.f + fexp2(-1.44269504088896f * x));
}
__device__ __forceinline__ unsigned cvtbf(float f) {   // f32->bf16 RNE
  unsigned u = __builtin_bit_cast(unsigned, f);
  return (u + 0x7fffu + ((u >> 16) & 1u)) >> 16;
}
__device__ __forceinline__ unsigned pack2(float a, float b) {
  return cvtbf(a) | (cvtbf(b) << 16);
}

// unordered pair table for geo basis k=1..7 (from _reduce_product; e_i^2=+1)
__device__ constexpr int PIdx[7][4][2] = {
  {{0,1},{2,4},{3,5},{6,7}},   // k=1 (e1)
  {{0,2},{1,4},{3,6},{5,7}},   // k=2 (e2)
  {{0,3},{1,5},{2,6},{4,7}},   // k=3 (e3)
  {{0,4},{1,2},{3,7},{5,6}},   // k=4 (e12)
  {{0,5},{1,3},{2,7},{4,6}},   // k=5 (e13)
  {{0,6},{1,7},{2,3},{4,5}},   // k=6 (e23)
  {{0,7},{1,6},{2,5},{3,4}}};  // k=7 (e123)

// ---- kernel 0: prep -------------------------------------------------------
// 768 blocks x 256 threads = 196608 = 3 * 128*512 weight elements.
__global__ __launch_bounds__(256) void k_prep(
    const float* __restrict__ W, const float* __restrict__ wg,
    const float* __restrict__ wu, const float* __restrict__ wd,
    const float* __restrict__ gg, char* __restrict__ ws) {
  int gid = blockIdx.x * 256 + threadIdx.x;
  if (gid < 65536) {                       // w_gate: (k,f) -> [fc][ks][g4][fl][e]
    int f = gid & 511, k = gid >> 9;
    unsigned short v = (unsigned short)cvtbf(wg[k * 512 + f]);
    int off = OFF_WG + (f >> 6) * 16384 + (k >> 5) * 4096 +
              ((k >> 3) & 3) * 1024 + (f & 63) * 16 + (k & 7) * 2;
    *(unsigned short*)(ws + off) = v;
  } else if (gid < 131072) {               // w_up
    int t = gid - 65536;
    int f = t & 511, k = t >> 9;
    unsigned short v = (unsigned short)cvtbf(wu[k * 512 + f]);
    int off = OFF_WU + (f >> 6) * 16384 + (k >> 5) * 4096 +
              ((k >> 3) & 3) * 1024 + (f & 63) * 16 + (k & 7) * 2;
    *(unsigned short*)(ws + off) = v;
  } else {                                 // w_down: (f,d) -> [fc][k2][g4][d][e]
    int t = gid - 131072;
    int d = t & 127, f = t >> 7;
    unsigned short v = (unsigned short)cvtbf(wd[f * 128 + d]);
    int off = OFF_WD + (f >> 6) * 16384 + ((f >> 5) & 1) * 8192 +
              ((f >> 3) & 3) * 2048 + d * 16 + (f & 7) * 2;
    *(unsigned short*)(ws + off) = v;
  }
  if (blockIdx.x == 0 && threadIdx.x == 0) {
    float s[64];
    for (int i = 0; i < 64; ++i) s[i] = fsigmoid(W[i]);
    float* C = (float*)(ws + OFF_C);
#define Sij(i, j) s[(i) * 8 + (j)]
    for (int i = 0; i < 8; ++i) C[i] = (i < 4 ? 1.f : -1.f) * Sij(i, i);
    C[8]  =  Sij(0,1) + Sij(1,0);  C[9]  = -Sij(2,4) + Sij(4,2);
    C[10] = -Sij(3,5) + Sij(5,3);  C[11] = -Sij(6,7) - Sij(7,6);
    C[12] =  Sij(0,2) + Sij(2,0);  C[13] =  Sij(1,4) - Sij(4,1);
    C[14] = -Sij(3,6) + Sij(6,3);  C[15] =  Sij(5,7) + Sij(7,5);
    C[16] =  Sij(0,3) + Sij(3,0);  C[17] =  Sij(1,5) - Sij(5,1);
    C[18] =  Sij(2,6) - Sij(6,2);  C[19] = -Sij(4,7) - Sij(7,4);
    C[20] =  Sij(0,4) + Sij(4,0);  C[21] =  Sij(1,2) - Sij(2,1);
    C[22] =  Sij(3,7) + Sij(7,3);  C[23] = -Sij(5,6) + Sij(6,5);
    C[24] =  Sij(0,5) + Sij(5,0);  C[25] =  Sij(1,3) - Sij(3,1);
    C[26] = -Sij(2,7) - Sij(7,2);  C[27] =  Sij(4,6) - Sij(6,4);
    C[28] =  Sij(0,6) + Sij(6,0);  C[29] =  Sij(1,7) + Sij(7,1);
    C[30] =  Sij(2,3) - Sij(3,2);  C[31] = -Sij(4,5) + Sij(5,4);
    C[32] =  Sij(0,7) + Sij(7,0);  C[33] =  Sij(1,6) + Sij(6,1);
    C[34] = -Sij(2,5) - Sij(5,2);  C[35] =  Sij(3,4) + Sij(4,3);
#undef Sij
    float gate = fsigmoid(gg[0]);
    C[36] = gate; C[37] = 1.f - gate;
  }
}

// ---- fused kernel (barrier-free) ------------------------------------------
__global__ __launch_bounds__(256, 2) void k_fused(
    const float* __restrict__ x,
    const float* __restrict__ gamma,
    const float* __restrict__ beta,
    const float* __restrict__ cws,
    float* __restrict__ out,
    const char* __restrict__ ws) {
  __shared__ __align__(16) char lds[32768];  // per-wave 8 KiB scratch / h_t
  const int tid = threadIdx.x, l = tid & 63, w = tid >> 6;
  const int r16 = l & 15, g4 = l >> 4;
  const long wrow0 = (long)blockIdx.x * 256 + (long)w * 64;

  char* scr = lds + w * 8192;

  // ---- phase 1: geo + mix + LN -> bn fragments ----------------------------
  float C[38];
#pragma unroll
  for (int i = 0; i < 38; ++i) C[i] = cws[i];  // uniform -> scalar
  const float gate = C[36], omg = C[37];

  bf16x8 bn[4][4];  // [row-tile][ks]: lane(g4,r16) holds k=ks*32+g4*8+e, row r16
#pragma unroll
  for (int p = 0; p < 4; ++p) {
#pragma unroll
    for (int hB = 0; hB < 2; ++hB) {
      const long r0 = wrow0 + p * 16 + hB * 8;
      float xa[8], xb[8];
#pragma unroll
      for (int n = 0; n < 8; ++n) {
        float2 v = *(const float2*)(x + (size_t)(r0 + n) * 128 + 2 * l);
        xa[n] = v.x; xb[n] = v.y;
      }
      float ga[8], gb[8];
      {
        float a0 = C[0] * xa[0] * xa[0], b0 = C[0] * xb[0] * xb[0];
#pragma unroll
        for (int i = 1; i < 8; ++i) {
          a0 = fmaf(C[i], xa[i] * xa[i], a0);
          b0 = fmaf(C[i], xb[i] * xb[i], b0);
        }
        ga[0] = a0; gb[0] = b0;
#pragma unroll
        for (int k = 1; k < 8; ++k) {
          float ta = 0.f, tb = 0.f;
#pragma unroll
          for (int q = 0; q < 4; ++q) {
            const int i = PIdx[k - 1][q][0], jj = PIdx[k - 1][q][1];
            const float c = C[8 + (k - 1) * 4 + q];
            ta = fmaf(c, xa[i] * xa[jj], ta);
            tb = fmaf(c, xb[i] * xb[jj], tb);
          }
          ga[k] = ta; gb[k] = tb;
        }
      }
#pragma unroll
      for (int n = 0; n < 8; ++n) {
        float2 m2;
        m2.x = fmaf(gate, ga[n], omg * xa[n]);
        m2.y = fmaf(gate, gb[n], omg * xb[n]);
        const int sr = hB * 8 + n;  // sr&7 == n
        *(float2*)(scr + sr * 512 + ((l * 8) ^ (n << 4))) = m2;
      }
    }
    // fragment read (transpose): lane(g4,r16) <- row r16, k = ks*32+g4*8+e
    f32x4 mx[4][2];
    float s = 0.f, ss = 0.f;
    const int swr = (r16 & 7) << 4;
#pragma unroll
    for (int ks = 0; ks < 4; ++ks)
#pragma unroll
      for (int hh = 0; hh < 2; ++hh) {
        f32x4 v = *(const f32x4*)(scr + r16 * 512 +
                                  ((ks * 128 + g4 * 32 + hh * 16) ^ swr));
        mx[ks][hh] = v;
#pragma unroll
        for (int e = 0; e < 4; ++e) { s += v[e]; ss = fmaf(v[e], v[e], ss); }
      }
    s  += __shfl_xor(s, 16);  s  += __shfl_xor(s, 32);
    ss += __shfl_xor(ss, 16); ss += __shfl_xor(ss, 32);
    const float mean = s * (1.f / 128.f);
    const float var  = fmaf(-mean, mean, ss * (1.f / 128.f));
    const float rstd = rsqrtf(var + 1e-5f);
#pragma unroll
    for (int ks = 0; ks < 4; ++ks) {
      const float4 gm0 = *(const float4*)(gamma + ks * 32 + g4 * 8);
      const float4 gm1 = *(const float4*)(gamma + ks * 32 + g4 * 8 + 4);
      const float4 be0 = *(const float4*)(beta + ks * 32 + g4 * 8);
      const float4 be1 = *(const float4*)(beta + ks * 32 + g4 * 8 + 4);
      float nv[8];
      nv[0] = fmaf((mx[ks][0][0] - mean) * rstd, gm0.x, be0.x);
      nv[1] = fmaf((mx[ks][0][1] - mean) * rstd, gm0.y, be0.y);
      nv[2] = fmaf((mx[ks][0][2] - mean) * rstd, gm0.z, be0.z);
      nv[3] = fmaf((mx[ks][0][3] - mean) * rstd, gm0.w, be0.w);
      nv[4] = fmaf((mx[ks][1][0] - mean) * rstd, gm1.x, be1.x);
      nv[5] = fmaf((mx[ks][1][1] - mean) * rstd, gm1.y, be1.y);
      nv[6] = fmaf((mx[ks][1][2] - mean) * rstd, gm1.z, be1.z);
      nv[7] = fmaf((mx[ks][1][3] - mean) * rstd, gm1.w, be1.w);
      uint4 uv;
      uv.x = pack2(nv[0], nv[1]); uv.y = pack2(nv[2], nv[3]);
      uv.z = pack2(nv[4], nv[5]); uv.w = pack2(nv[6], nv[7]);
      bn[p][ks] = __builtin_bit_cast(bf16x8, uv);
    }
  }

  // ---- chunk loop (weights streamed from global / L2) ---------------------
  f32x4 acc[8][4];
#pragma unroll
  for (int dt = 0; dt < 8; ++dt)
#pragma unroll
    for (int rt = 0; rt < 4; ++rt) acc[dt][rt] = f32x4{0.f, 0.f, 0.f, 0.f};

  char* lht = scr;  // per-wave [64 rows][64 f] bf16, swizzled
  const char* wsg = ws + OFF_WG + g4 * 1024;
  const char* wsu = ws + OFF_WU + g4 * 1024;
  const char* wsd = ws + OFF_WD + g4 * 2048;

  for (int fc = 0; fc < 8; ++fc) {
    const int cb = fc * 16384;
    // GEMM1: C'[f][row] = Wg[f][k] x normed[row][k]; silu*up -> h_t
#pragma unroll
    for (int ft = 0; ft < 4; ++ft) {
      const int fo = (ft * 16 + r16) * 16;
      bf16x8 ag[4], au[4];
#pragma unroll
      for (int ks = 0; ks < 4; ++ks) {
        ag[ks] = *(const bf16x8*)(wsg + cb + ks * 4096 + fo);
        au[ks] = *(const bf16x8*)(wsu + cb + ks * 4096 + fo);
      }
#pragma unroll
      for (int rt = 0; rt < 4; ++rt) {
        f32x4 cg = {0.f, 0.f, 0.f, 0.f}, cu = {0.f, 0.f, 0.f, 0.f};
#pragma unroll
        for (int ks = 0; ks < 4; ++ks) {
          cg = MFMA16(ag[ks], bn[rt][ks], cg);
          cu = MFMA16(au[ks], bn[rt][ks], cu);
        }
        const float h0 = cg[0] * cu[0] * frcp(1.f + fexp2(-1.44269504f * cg[0]));
        const float h1 = cg[1] * cu[1] * frcp(1.f + fexp2(-1.44269504f * cg[1]));
        const float h2 = cg[2] * cu[2] * frcp(1.f + fexp2(-1.44269504f * cg[2]));
        const float h3 = cg[3] * cu[3] * frcp(1.f + fexp2(-1.44269504f * cg[3]));
        uint2 hv; hv.x = pack2(h0, h1); hv.y = pack2(h2, h3);
        const int row = rt * 16 + r16;
        *(uint2*)(lht + row * 128 + ((ft * 32 + g4 * 8) ^ ((row & 7) << 4))) = hv;
      }
    }
    // GEMM2: out'[d][row] += Wd[d][f'] x h[row][f']
    bf16x8 hb[4][2];
#pragma unroll
    for (int rt = 0; rt < 4; ++rt)
#pragma unroll
      for (int k2 = 0; k2 < 2; ++k2) {
        const int row = rt * 16 + r16;
        hb[rt][k2] = *(const bf16x8*)(lht + row * 128 +
                                      ((k2 * 64 + g4 * 16) ^ ((row & 7) << 4)));
      }
#pragma unroll
    for (int dt = 0; dt < 8; ++dt) {
      const int dofs = (dt * 16 + r16) * 16;
      bf16x8 w0 = *(const bf16x8*)(wsd + cb + dofs);
      bf16x8 w1 = *(const bf16x8*)(wsd + cb + 8192 + dofs);
#pragma unroll
      for (int rt = 0; rt < 4; ++rt) {
        acc[dt][rt] = MFMA16(w0, hb[rt][0], acc[dt][rt]);
        acc[dt][rt] = MFMA16(w1, hb[rt][1], acc[dt][rt]);
      }
    }
  }

  // ---- epilogue: out = x + acc -------------------------------------------
#pragma unroll
  for (int dt = 0; dt < 8; ++dt)
#pragma unroll
    for (int rt = 0; rt < 4; ++rt) {
      const size_t row = (size_t)(wrow0 + rt * 16 + r16);
      const int db = dt * 16 + g4 * 4;
      const float4 xv = *(const float4*)(x + row * 128 + db);
      float4 o;
      o.x = acc[dt][rt][0] + xv.x;
      o.y = acc[dt][rt][1] + xv.y;
      o.z = acc[dt][rt][2] + xv.z;
      o.w = acc[dt][rt][3] + xv.w;
      *(float4*)(out + row * 128 + db) = o;
    }
}

// ---------------------------------------------------------------------------

extern "C" void kernel_launch(void* const* d_in, const int* in_sizes, int n_in,
                              void* d_out, int out_size, void* d_ws, size_t ws_size,
                              hipStream_t stream) {
  (void)in_sizes; (void)n_in; (void)out_size; (void)ws_size;
  const float* x     = (const float*)d_in[0];
  const float* W     = (const float*)d_in[1];
  const float* wg    = (const float*)d_in[2];
  const float* wu    = (const float*)d_in[3];
  const float* wd    = (const float*)d_in[4];
  const float* gamma = (const float*)d_in[5];
  const float* beta  = (const float*)d_in[6];
  const float* gg    = (const float*)d_in[7];
  char* ws = (char*)d_ws;

  k_prep<<<768, 256, 0, stream>>>(W, wg, wu, wd, gg, ws);
  k_fused<<<512, 256, 0, stream>>>(x, gamma, beta, (const float*)(ws + OFF_C),
                                   (float*)d_out, ws);
}